// Round 15
// baseline (6137.241 us; speedup 1.0000x reference)
//
#include <hip/hip_runtime.h>

#define DI __device__ __forceinline__

typedef __attribute__((ext_vector_type(4))) float  f32x4;
typedef __attribute__((ext_vector_type(8))) short  s16x8;
typedef __attribute__((ext_vector_type(8))) __bf16 bf16x8;
typedef unsigned long long u64;

// ---------------- constants ----------------
constexpr int S_   = 256;
constexpr int B_   = 512;
constexpr int KP_  = 320;   // padded 300
constexpr int ALD_ = 832;   // act row: [xt 0..320 | htm 320..832]
constexpr int NRING = 34;
constexpr int NWG  = 512;   // 16 groups x 32 WGs; 2 WGs per CU
constexpr size_t HSLOT = 512 * 512;

// ---------------- workspace layout (bytes) ----------------
constexpr size_t OFF_XIN = 0;                              // bf16 [S][B][320]
constexpr size_t SZ_XIN  = (size_t)S_ * B_ * KP_ * 2;
constexpr size_t OFF_U   = OFF_XIN + SZ_XIN;               // f32 [B][S][64]
constexpr size_t SZ_U    = (size_t)B_ * S_ * 64 * 4;
constexpr size_t OFF_HS  = OFF_U + SZ_U;                   // bf16 ring [34][512][512]
constexpr size_t SZ_HS   = (size_t)NRING * HSLOT * 2;
constexpr size_t OFF_ACT = OFF_HS + SZ_HS;                 // bf16 [512][832]
constexpr size_t SZ_ACT  = (size_t)B_ * ALD_ * 2;
constexpr size_t OFF_WPT = OFF_ACT + SZ_ACT;               // bf16 [320][320]
constexpr size_t SZ_WPT  = (size_t)320 * 320 * 2;
constexpr size_t OFF_QPT = OFF_WPT + SZ_WPT;               // bf16 [320][512]
constexpr size_t SZ_QPT  = (size_t)320 * 512 * 2;
constexpr size_t OFF_RPT = OFF_QPT + SZ_QPT;               // bf16 [512][320]
constexpr size_t SZ_RPT  = (size_t)512 * 320 * 2;
constexpr size_t OFF_WGT = OFF_RPT + SZ_RPT;               // bf16 [2048][832], n'=4c+g
constexpr size_t SZ_WGT  = (size_t)2048 * 832 * 2;
constexpr size_t OFF_BG  = OFF_WGT + SZ_WGT;               // f32 [2048], n' order
constexpr size_t SZ_BG   = 2048 * 4;
constexpr size_t OFF_VT  = OFF_BG + SZ_BG;                 // bf16 [64][512]
constexpr size_t SZ_VT   = (size_t)64 * 512 * 2;
constexpr size_t OFF_BAR = OFF_VT + SZ_VT;                 // u32 flag lines
constexpr size_t SZ_BAR  = 8192;
constexpr size_t WS_NEED = OFF_BAR + SZ_BAR;

// ---------------- helpers ----------------
DI unsigned short f2bf(float x) {
  unsigned int u = __float_as_uint(x);
  unsigned int r = (u + 0x7FFFu + ((u >> 16) & 1u)) >> 16;
  return (unsigned short)r;
}
DI float bf2f(unsigned short h) { return __uint_as_float(((unsigned int)h) << 16); }

DI float sigm(float x) {
  float e = __builtin_amdgcn_exp2f(x * -1.44269504088896f);
  return __builtin_amdgcn_rcpf(1.0f + e);
}
DI float tanh_(float x) {
  x = fminf(fmaxf(x, -15.0f), 15.0f);
  float e = __builtin_amdgcn_exp2f(x * 2.88539008177793f);
  return (e - 1.0f) * __builtin_amdgcn_rcpf(e + 1.0f);
}
DI bf16x8 asbf(s16x8 v) { return __builtin_bit_cast(bf16x8, v); }

// ---- LLC-coherent (sc0 sc1) accesses, compiler-managed ----
DI u64 ld_sys_u64(const void* p) {
  return __hip_atomic_load((const u64*)p, __ATOMIC_RELAXED, __HIP_MEMORY_SCOPE_SYSTEM);
}
DI void st_sys_u64(void* p, u64 v) {
  __hip_atomic_store((u64*)p, v, __ATOMIC_RELAXED, __HIP_MEMORY_SCOPE_SYSTEM);
}
DI unsigned int ld_sys_u32(const unsigned int* p) {
  return __hip_atomic_load(p, __ATOMIC_RELAXED, __HIP_MEMORY_SCOPE_SYSTEM);
}
DI void st_sys_u32(unsigned int* p, unsigned int v) {
  __hip_atomic_store(p, v, __ATOMIC_RELAXED, __HIP_MEMORY_SCOPE_SYSTEM);
}
template<int N> DI void wait_vm() {
  asm volatile("s_waitcnt vmcnt(%0)" :: "n"(N) : "memory");
}

// ---------------- 2-team K-split GEMM, M=32 N=64 (512 threads) ------------
// Team tm = tid>>8 (4 waves) handles k-tiles {tm, tm+2, ...} into acc[2]
// (wave tile 16x32). A (32 rows) via sc0sc1 u64 (MALL-coherent act/h) with
// DEPTH-4 round prefetch (covers ~1000cy MALL latency); B (64 B^T rows)
// plain cached (L2-hot weights), depth-2. LDS per team: 2 bufs x (A 2KB +
// B 4KB).
template<int NK>
DI void gemm2(const unsigned short* Ab, int lda,
              const unsigned short* Bb, int ldb,
              short* sA, short* sB, f32x4 acc[2])
{
  constexpr int NR = (NK + 1) / 2;
  const int tid  = threadIdx.x;
  const int tm   = tid >> 8;
  const int t8   = tid & 255;
  const int lane = tid & 63;
  const int l15  = lane & 15;
  const int kseg = (lane >> 4) * 8;
  const int w    = (tid >> 6) & 3;
  const int wm = w >> 1, wn = w & 1;
  const int sArow = t8 >> 3, sAcol = (t8 & 7) * 4;
  const int sBrow = t8 >> 2, sBcol = (t8 & 3) * 8;
  const unsigned short* gA = Ab + sArow * lda + sAcol;
  const unsigned short* gB = Bb + sBrow * ldb + sBcol;
  short* tA = sA + tm * 2048;
  short* tB = sB + tm * 4096;
  const int aoff = sArow * 32 + sAcol;
  const int boff = sBrow * 32 + sBcol;
  const int afr  = (wm * 16 + l15) * 32 + kseg;

  u64 a[4] = {}, b0[2] = {}, b1[2] = {};
  #pragma unroll
  for (int r = 0; r < 4; ++r)
    if (r < NR && r * 2 + tm < NK) a[r] = ld_sys_u64(gA + (r * 2 + tm) * 32);
  #pragma unroll
  for (int r = 0; r < 2; ++r)
    if (r < NR && r * 2 + tm < NK) {
      b0[r] = ((const u64*)(gB + (r * 2 + tm) * 32))[0];
      b1[r] = ((const u64*)(gB + (r * 2 + tm) * 32))[1];
    }
  *(u64*)&tA[aoff] = a[0];
  *(u64*)&tB[boff] = b0[0]; *(u64*)&tB[boff + 4] = b1[0];
  __syncthreads();
  #pragma unroll
  for (int j = 0; j < NR; ++j) {
    const int curA = (j & 1) * 1024, curB = (j & 1) * 2048;
    {
      const int ka = (j + 4) * 2 + tm;      // A prefetch depth 4
      if (j + 4 < NR && ka < NK) a[j & 3] = ld_sys_u64(gA + ka * 32);
      const int kb = (j + 2) * 2 + tm;      // B prefetch depth 2
      if (j + 2 < NR && kb < NK) {
        b0[j & 1] = ((const u64*)(gB + kb * 32))[0];
        b1[j & 1] = ((const u64*)(gB + kb * 32))[1];
      }
    }
    if (j * 2 + tm < NK) {
      s16x8 Af = *(const s16x8*)&tA[curA + afr];
      #pragma unroll
      for (int ni = 0; ni < 2; ++ni) {
        s16x8 Bf = *(const s16x8*)&tB[curB + (wn * 32 + ni * 16 + l15) * 32 + kseg];
        acc[ni] = __builtin_amdgcn_mfma_f32_16x16x32_bf16(asbf(Af), asbf(Bf), acc[ni], 0, 0, 0);
      }
    }
    if (j + 1 < NR) {
      const int kt = (j + 1) * 2 + tm;
      const int nxtA = ((j + 1) & 1) * 1024, nxtB = ((j + 1) & 1) * 2048;
      if (kt < NK) {
        *(u64*)&tA[nxtA + aoff] = a[(j + 1) & 3];
        *(u64*)&tB[nxtB + boff] = b0[(j + 1) & 1];
        *(u64*)&tB[nxtB + boff + 4] = b1[(j + 1) & 1];
      }
    }
    __syncthreads();
  }
}

// team1 acc -> rbuf [8][256] (stride-1), team0 adds into its acc
DI void reduce2(f32x4 acc[2], float* rbuf) {
  const int tid = threadIdx.x, t8 = tid & 255;
  if (tid >= 256) {
    #pragma unroll
    for (int ni = 0; ni < 2; ++ni)
      #pragma unroll
      for (int r = 0; r < 4; ++r)
        rbuf[(ni * 4 + r) * 256 + t8] = acc[ni][r];
  }
  __syncthreads();
  if (tid < 256) {
    #pragma unroll
    for (int ni = 0; ni < 2; ++ni)
      #pragma unroll
      for (int r = 0; r < 4; ++r)
        acc[ni][r] += rbuf[(ni * 4 + r) * 256 + t8];
  }
}

// team0 epilogue iterator over the 32x64 tile: f(row, col, val)
template<typename F>
DI void epiloop32(f32x4 acc[2], F&& f) {
  const int lane = threadIdx.x & 63;
  const int w = (threadIdx.x >> 6) & 3, wm = w >> 1, wn = w & 1;
  #pragma unroll
  for (int ni = 0; ni < 2; ++ni)
    #pragma unroll
    for (int r = 0; r < 4; ++r)
      f(wm * 16 + (lane >> 4) * 4 + r, wn * 32 + ni * 16 + (lane & 15), acc[ni][r]);
}

// pack-store a 32x64 u16 LDS tile to system memory (512 threads, 1 u64 each)
DI void pack_store32(const unsigned short* lds16, unsigned short* dstbase, int ldd) {
  const u64* l64 = (const u64*)lds16;
  const int i = threadIdx.x;
  const int row = i >> 4, q = i & 15;
  st_sys_u64(dstbase + row * ldd + q * 4, l64[i]);
}

// ---------------- k_proj building blocks (256 threads) ----------
template<int NK, int KREAL>
DI void gemm_f32A(const float* Af, int lda,
                  const unsigned short* Bb, int ldb,
                  short* sA, short* sB, f32x4 acc[2][2])
{
  const int tid  = threadIdx.x;
  const int lane = tid & 63;
  const int w = tid >> 6, wm = w >> 1, wn = w & 1;
  const float* ga = Af + (tid >> 2) * lda;
  const int cseg  = (tid & 3) * 8;
  const unsigned short* gb = Bb + (tid >> 2) * ldb + (tid & 3) * 8;
  const int arow0 = (wm * 32 + (lane & 15)) * 32 + (lane >> 4) * 8;
  const int brow0 = (wn * 32 + (lane & 15)) * 32 + (lane >> 4) * 8;

  auto loadA = [&](int k) -> s16x8 {
    s16x8 r;
    const int c0 = k * 32 + cseg;
    if (c0 + 8 <= KREAL) {
      float4 f0 = *(const float4*)(ga + c0);
      float4 f1 = *(const float4*)(ga + c0 + 4);
      r[0] = (short)f2bf(f0.x); r[1] = (short)f2bf(f0.y);
      r[2] = (short)f2bf(f0.z); r[3] = (short)f2bf(f0.w);
      r[4] = (short)f2bf(f1.x); r[5] = (short)f2bf(f1.y);
      r[6] = (short)f2bf(f1.z); r[7] = (short)f2bf(f1.w);
    } else {
      #pragma unroll
      for (int j = 0; j < 8; ++j) {
        float x = (c0 + j < KREAL) ? ga[c0 + j] : 0.0f;
        r[j] = (short)f2bf(x);
      }
    }
    return r;
  };

  s16x8 va = loadA(0);
  s16x8 vb = *(const s16x8*)gb;
  *(s16x8*)&sA[tid * 8] = va;
  *(s16x8*)&sB[tid * 8] = vb;
  __syncthreads();
  for (int k = 0; k < NK; ++k) {
    const int cur = (k & 1) * 2048;
    if (k + 1 < NK) {
      va = loadA(k + 1);
      vb = *(const s16x8*)(gb + (k + 1) * 32);
    }
    s16x8 a0 = *(const s16x8*)&sA[cur + arow0];
    s16x8 a1 = *(const s16x8*)&sA[cur + arow0 + 16 * 32];
    s16x8 b0 = *(const s16x8*)&sB[cur + brow0];
    s16x8 b1 = *(const s16x8*)&sB[cur + brow0 + 16 * 32];
    acc[0][0] = __builtin_amdgcn_mfma_f32_16x16x32_bf16(asbf(a0), asbf(b0), acc[0][0], 0, 0, 0);
    acc[0][1] = __builtin_amdgcn_mfma_f32_16x16x32_bf16(asbf(a0), asbf(b1), acc[0][1], 0, 0, 0);
    acc[1][0] = __builtin_amdgcn_mfma_f32_16x16x32_bf16(asbf(a1), asbf(b0), acc[1][0], 0, 0, 0);
    acc[1][1] = __builtin_amdgcn_mfma_f32_16x16x32_bf16(asbf(a1), asbf(b1), acc[1][1], 0, 0, 0);
    if (k + 1 < NK) {
      const int nxt = ((k + 1) & 1) * 2048;
      *(s16x8*)&sA[nxt + tid * 8] = va;
      *(s16x8*)&sB[nxt + tid * 8] = vb;
    }
    __syncthreads();
  }
}

template<typename F>
DI void epiloop(f32x4 acc[2][2], F&& f) {
  const int lane = threadIdx.x & 63;
  const int w = (threadIdx.x & 255) >> 6, wm = w >> 1, wn = w & 1;
  #pragma unroll
  for (int mi = 0; mi < 2; ++mi)
    #pragma unroll
    for (int ni = 0; ni < 2; ++ni)
      #pragma unroll
      for (int r = 0; r < 4; ++r) {
        const int rowl = wm * 32 + mi * 16 + (lane >> 4) * 4 + r;
        const int coll = wn * 32 + ni * 16 + (lane & 15);
        f(rowl, coll, acc[mi][ni][r]);
      }
}

// ---------------- prep kernels ----------------
__global__ void k_prep_wpt(const float* __restrict__ Wi, unsigned short* __restrict__ WpT) {
  int i = blockIdx.x * 256 + threadIdx.x;
  if (i >= 320 * 320) return;
  int n = i / 320, k = i % 320;
  float v = (n < 300 && k < 300) ? Wi[k * 300 + n] : 0.0f;
  WpT[i] = f2bf(v);
}
__global__ void k_prep_qpt(const float* __restrict__ Q, unsigned short* __restrict__ QpT) {
  int i = blockIdx.x * 256 + threadIdx.x;
  if (i >= 320 * 512) return;
  int n = i >> 9, k = i & 511;
  float v = (n < 300) ? Q[k * 300 + n] : 0.0f;
  QpT[i] = f2bf(v);
}
__global__ void k_prep_rpt(const float* __restrict__ R, unsigned short* __restrict__ RpT) {
  int i = blockIdx.x * 256 + threadIdx.x;
  if (i >= 512 * 320) return;
  int n = i / 320, k = i % 320;
  float v = (k < 300) ? R[k * 512 + n] : 0.0f;
  RpT[i] = f2bf(v);
}
// n' = 4c+g ordering: col = g*512 + c
__global__ void k_prep_wgt(const float* __restrict__ Wih, const float* __restrict__ Whh,
                           unsigned short* __restrict__ WgT) {
  int i = blockIdx.x * 256 + threadIdx.x;
  if (i >= 2048 * 832) return;
  int np = i / 832, k = i % 832;
  int c = np >> 2, g = np & 3, col = g * 512 + c;
  float v = 0.0f;
  if (k < 300) v = Wih[k * 2048 + col];
  else if (k >= 320) v = Whh[(k - 320) * 2048 + col];
  WgT[i] = f2bf(v);
}
__global__ void k_prep_bg(const float* __restrict__ bih, const float* __restrict__ bhh,
                          float* __restrict__ bg) {
  int i = blockIdx.x * 256 + threadIdx.x;
  if (i >= 2048) return;
  int c = i >> 2, g = i & 3, col = g * 512 + c;
  bg[i] = bih[col] + bhh[col];
}
__global__ void k_prep_vt(const float* __restrict__ Wc3, const float* __restrict__ Wc4,
                          const float* __restrict__ Wc5, unsigned short* __restrict__ VT) {
  int i = blockIdx.x * 256 + threadIdx.x;
  if (i >= 64 * 512) return;
  int j = i >> 9, k = i & 511;
  float v = 0.0f;
  if (j < 9)       { int f = j / 3,  dt = j % 3;        v = Wc3[(f * 3 + dt) * 512 + k]; }
  else if (j < 21) { int jj = j - 9;  int f = jj / 4, dt = jj % 4; v = Wc4[(f * 4 + dt) * 512 + k]; }
  else if (j < 36) { int jj = j - 21; int f = jj / 5, dt = jj % 5; v = Wc5[(f * 5 + dt) * 512 + k]; }
  VT[i] = f2bf(v);
}
__global__ void k_wsfail(float* out, int n, float v) {
  int i = blockIdx.x * 256 + threadIdx.x;
  if (i < n) out[i] = -v;
}

// ---------------- input projection ----------------
__global__ __launch_bounds__(256) void k_proj(const float* __restrict__ x,
                                              const unsigned short* __restrict__ WpT,
                                              const float* __restrict__ b_in,
                                              unsigned short* __restrict__ xin) {
  __shared__ short sA[4096], sB[4096];
  const int m0 = blockIdx.x * 64, n0 = blockIdx.y * 64;
  f32x4 acc[2][2];
  const f32x4 z = {0.f, 0.f, 0.f, 0.f};
  acc[0][0] = z; acc[0][1] = z; acc[1][0] = z; acc[1][1] = z;
  gemm_f32A<10, 300>(x + (size_t)m0 * 300, 300, WpT + n0 * 320, 320, sA, sB, acc);
  epiloop(acc, [&](int rowl, int coll, float vacc) {
    const int row = m0 + rowl, col = n0 + coll;
    float o = 0.0f;
    if (col < 300) o = tanh_(vacc + b_in[col]);
    const int b = row >> 8, s = row & 255;
    xin[(size_t)(s * 512 + b) * KP_ + col] = f2bf(o);
  });
}

// ---------------- persistent scan kernel ----------------
// 512 WGs x 512 threads = 16 independent groups of 32 WGs; group g owns
// batch rows 32g..32g+31. Two WGs co-resident per CU (48KB LDS each).
// Cross-WG data via sc0sc1 only. Barrier: per-WG epoch-flag stores in one
// 128B line + all-wave 64-lane __all poll (no serialized RMW, no release hop).
__global__ __launch_bounds__(512, 4) void k_scan(
    const unsigned short* __restrict__ xin,
    const unsigned short* __restrict__ QpT,
    const unsigned short* __restrict__ RpT,
    const unsigned short* __restrict__ WgT,
    const float* __restrict__ bg,
    const unsigned short* __restrict__ VT,
    unsigned short* __restrict__ hs,
    unsigned short* __restrict__ act,
    float* __restrict__ U,
    unsigned int* __restrict__ bar)
{
  __shared__ short sA[4096];                  // 2 teams x 2 bufs x 1024
  __shared__ short sB[8192];                  // 2 teams x 2 bufs x 2048
  __shared__ float rbuf[2048];                // team reduction (8KB)
  __shared__ float gbuf[2048];                // P3 gates f32 32x64 (8KB)
  __shared__ unsigned short pbuf[2048];       // 32x64 bf16 preload (4KB)
  __shared__ unsigned short obuf[2048];       // 32x64 bf16 out staging (4KB)
  const int wg   = blockIdx.x;
  const int grp  = wg >> 5;       // 16 groups; rows 32*grp .. 32*grp+31
  const int l    = wg & 31;
  const int tid  = threadIdx.x;
  const int lane = tid & 63;
  const f32x4 z = {0.f, 0.f, 0.f, 0.f};

  const int gm0 = grp * 32;             // batch-row tile
  const int gn0 = l * 64;               // P3 gate-col tile (n' order)
  float c_state = 0.f;                  // 1 cell/thread (32 rows x 16 hc)
  const int crow = tid >> 4, ccl = tid & 15;       // cell coords
  const float4 cb = *(const float4*)&bg[gn0 + ccl * 4];

  unsigned int* flags = bar + grp * 32;   // this group's 128B flag line
  int ep = 0;
  auto bar_sync = [&]() {
    wait_vm<0>();        // drain own sc-stores to LLC
    __syncthreads();     // all waves of this WG drained + arrived
    const unsigned tag = (unsigned)(ep + 1);
    if (tid == 0) st_sys_u32(&flags[l], tag);
    while (!__all(ld_sys_u32(&flags[lane & 31]) >= tag))
      __builtin_amdgcn_s_sleep(1);
    ++ep;
  };

  for (int t = 0; t < S_; ++t) {
    const unsigned short* hst = hs + (size_t)(t % NRING) * HSLOT;
    unsigned short*       hso = hs + (size_t)((t + 1) % NRING) * HSLOT;

    // hoisted preloads (latency hides under P1's whole phase)
    u64 xpre = 0, hpre = 0;
    const int prow = tid >> 4, pq = tid & 15;
    if (l < 5)
      xpre = *(const u64*)(xin + ((size_t)t * 512 + gm0 + prow) * KP_ + l * 64 + pq * 4);
    if (l < 8)
      hpre = ld_sys_u64(hst + (gm0 + prow) * 512 + l * 64 + pq * 4);

    // ---- P1: act[:,0:320] = 2*sigm(h_{t-1} @ Q) * xin_t  (5 tiles of 32x64)
    if (l < 5) {
      const int n0 = l * 64;
      ((u64*)pbuf)[tid] = xpre;   // value already in reg
      f32x4 acc[2] = {z, z};
      gemm2<16>(hst + gm0 * 512, 512, QpT + n0 * 512, 512, sA, sB, acc);
      reduce2(acc, rbuf);
      if (tid < 256) {
        epiloop32(acc, [&](int row, int col, float v) {
          obuf[row * 64 + col] = f2bf(2.0f * sigm(v) * bf2f(pbuf[row * 64 + col]));
        });
      }
      __syncthreads();
      pack_store32(obuf, act + gm0 * ALD_ + n0, ALD_);
    }
    bar_sync();

    // ---- P2: act[:,320:832] = 2*sigm(xt @ R) * h_{t-1}  (8 tiles)
    if (l < 8) {
      const int n0 = l * 64;
      ((u64*)pbuf)[tid] = hpre;   // value already in reg (loaded at step start)
      f32x4 acc[2] = {z, z};
      gemm2<10>(act + gm0 * ALD_, ALD_, RpT + n0 * KP_, KP_, sA, sB, acc);
      reduce2(acc, rbuf);
      if (tid < 256) {
        epiloop32(acc, [&](int row, int col, float v) {
          obuf[row * 64 + col] = f2bf(2.0f * sigm(v) * bf2f(pbuf[row * 64 + col]));
        });
      }
      __syncthreads();
      pack_store32(obuf, act + gm0 * ALD_ + 320 + n0, ALD_);
    }
    bar_sync();

    // ---- P3: gates GEMM + in-register cell update (32 tiles)
    {
      f32x4 acc[2] = {z, z};
      gemm2<26>(act + gm0 * ALD_, ALD_, WgT + gn0 * 832, 832, sA, sB, acc);
      reduce2(acc, rbuf);
      if (tid < 256) {
        epiloop32(acc, [&](int row, int col, float v) {
          gbuf[row * 64 + col] = v;
        });
      }
      __syncthreads();
      {  // 512 cells: thread (crow, ccl)
        const float iv = gbuf[crow * 64 + ccl * 4 + 0] + cb.x;
        const float fv = gbuf[crow * 64 + ccl * 4 + 1] + cb.y;
        const float gv = gbuf[crow * 64 + ccl * 4 + 2] + cb.z;
        const float ov = gbuf[crow * 64 + ccl * 4 + 3] + cb.w;
        const float cn = sigm(fv) * c_state + sigm(iv) * tanh_(gv);
        const float h  = sigm(ov) * tanh_(cn);
        c_state = cn;
        obuf[crow * 16 + ccl] = f2bf(h);
      }
      __syncthreads();
      if (tid < 128) {   // store h slice (32 rows x 16 cols) to ring
        const u64* h64 = (const u64*)obuf;
        const int row = tid >> 2, q = tid & 3;
        st_sys_u64(hso + (gm0 + row) * 512 + l * 16 + q * 4, h64[row * 4 + q]);
      }
    }
    bar_sync();

    // ---- convU every 32 steps: WG l covers timestep 32c+l for its rows
    if ((t & 31) == 31) {
      const int c = t >> 5;
      const int tglob = 32 * c + l;
      const int slot = (tglob + 1) % NRING;
      f32x4 acc[2] = {z, z};
      gemm2<16>(hs + (size_t)slot * HSLOT + (size_t)gm0 * 512, 512, VT, 512, sA, sB, acc);
      reduce2(acc, rbuf);
      if (tid < 256) {
        epiloop32(acc, [&](int row, int col, float v) {
          U[((size_t)(gm0 + row) * 256 + tglob) * 64 + col] = v;
        });
      }
      __syncthreads();
    }
  }
}

// window-sum + relu + global max pool + final linear
__global__ __launch_bounds__(256) void k_combine(const float* __restrict__ U,
                                                 const float* __restrict__ bc3,
                                                 const float* __restrict__ bc4,
                                                 const float* __restrict__ bc5,
                                                 const float* __restrict__ Wl,
                                                 const float* __restrict__ bl,
                                                 float* __restrict__ out) {
  const int b = blockIdx.x;
  const int p = threadIdx.x;
  const float* Ub = U + (size_t)b * (256 * 64);
  float v[9];
  #pragma unroll
  for (int j = 0; j < 9; ++j) v[j] = -1e30f;
  if (p < 254) {
    #pragma unroll
    for (int f = 0; f < 3; ++f)
      v[f] = Ub[(p + 0) * 64 + f * 3 + 0] + Ub[(p + 1) * 64 + f * 3 + 1] + Ub[(p + 2) * 64 + f * 3 + 2];
  }
  if (p < 253) {
    #pragma unroll
    for (int f = 0; f < 3; ++f)
      v[3 + f] = Ub[(p + 0) * 64 + 9 + f * 4 + 0] + Ub[(p + 1) * 64 + 9 + f * 4 + 1] +
                 Ub[(p + 2) * 64 + 9 + f * 4 + 2] + Ub[(p + 3) * 64 + 9 + f * 4 + 3];
  }
  if (p < 252) {
    #pragma unroll
    for (int f = 0; f < 3; ++f)
      v[6 + f] = Ub[(p + 0) * 64 + 21 + f * 5 + 0] + Ub[(p + 1) * 64 + 21 + f * 5 + 1] +
                 Ub[(p + 2) * 64 + 21 + f * 5 + 2] + Ub[(p + 3) * 64 + 21 + f * 5 + 3] +
                 Ub[(p + 4) * 64 + 21 + f * 5 + 4];
  }
  __shared__ float red[4][9];
  const int lane = threadIdx.x & 63, w = threadIdx.x >> 6;
  #pragma unroll
  for (int j = 0; j < 9; ++j) {
    float m = v[j];
    #pragma unroll
    for (int off = 32; off >= 1; off >>= 1) m = fmaxf(m, __shfl_xor(m, off));
    if (lane == 0) red[w][j] = m;
  }
  __syncthreads();
  if (threadIdx.x < 2) {
    const int k = threadIdx.x;
    float o = bl[k];
    #pragma unroll
    for (int j = 0; j < 9; ++j) {
      float m = fmaxf(fmaxf(red[0][j], red[1][j]), fmaxf(red[2][j], red[3][j]));
      float bias = (j < 3) ? bc3[j] : (j < 6) ? bc4[j - 3] : bc5[j - 6];
      o += fmaxf(m + bias, 0.0f) * Wl[j * 2 + k];
    }
    out[b * 2 + k] = o;
  }
}

// ---------------- host launch ----------------
extern "C" void kernel_launch(void* const* d_in, const int* in_sizes, int n_in,
                              void* d_out, int out_size, void* d_ws, size_t ws_size,
                              hipStream_t stream) {
  const float* x     = (const float*)d_in[0];
  const float* W_in  = (const float*)d_in[1];
  const float* b_in  = (const float*)d_in[2];
  const float* Wih   = (const float*)d_in[3];
  const float* Whh   = (const float*)d_in[4];
  const float* bih   = (const float*)d_in[5];
  const float* bhh   = (const float*)d_in[6];
  const float* Q     = (const float*)d_in[7];
  const float* R     = (const float*)d_in[8];
  const float* Wc3   = (const float*)d_in[9];
  const float* bc3   = (const float*)d_in[10];
  const float* Wc4   = (const float*)d_in[11];
  const float* bc4   = (const float*)d_in[12];
  const float* Wc5   = (const float*)d_in[13];
  const float* bc5   = (const float*)d_in[14];
  const float* W_lin = (const float*)d_in[15];
  const float* b_lin = (const float*)d_in[16];

  if (ws_size < WS_NEED) {
    k_wsfail<<<4, 256, 0, stream>>>((float*)d_out, out_size, (float)(ws_size >> 20));
    return;
  }

  char* ws = (char*)d_ws;
  unsigned short* xin = (unsigned short*)(ws + OFF_XIN);
  float*          U   = (float*)(ws + OFF_U);
  unsigned short* hs  = (unsigned short*)(ws + OFF_HS);
  unsigned short* act = (unsigned short*)(ws + OFF_ACT);
  unsigned short* WpT = (unsigned short*)(ws + OFF_WPT);
  unsigned short* QpT = (unsigned short*)(ws + OFF_QPT);
  unsigned short* RpT = (unsigned short*)(ws + OFF_RPT);
  unsigned short* WgT = (unsigned short*)(ws + OFF_WGT);
  float*          bg  = (float*)(ws + OFF_BG);
  unsigned short* VT  = (unsigned short*)(ws + OFF_VT);
  unsigned int*   bar = (unsigned int*)(ws + OFF_BAR);

  // per-replay init: h0 = 0 (ring slot 0), flags = 0
  (void)hipMemsetAsync(hs, 0, HSLOT * 2, stream);
  (void)hipMemsetAsync(bar, 0, SZ_BAR, stream);

  // weight prep
  k_prep_wpt<<<(320 * 320 + 255) / 256, 256, 0, stream>>>(W_in, WpT);
  k_prep_qpt<<<(320 * 512 + 255) / 256, 256, 0, stream>>>(Q, QpT);
  k_prep_rpt<<<(512 * 320 + 255) / 256, 256, 0, stream>>>(R, RpT);
  k_prep_wgt<<<(2048 * 832 + 255) / 256, 256, 0, stream>>>(Wih, Whh, WgT);
  k_prep_bg<<<8, 256, 0, stream>>>(bih, bhh, bg);
  k_prep_vt<<<(64 * 512 + 255) / 256, 256, 0, stream>>>(Wc3, Wc4, Wc5, VT);

  // input projection
  k_proj<<<dim3(131072 / 64, KP_ / 64), 256, 0, stream>>>(x, WpT, b_in, xin);

  // persistent scan: 512 WGs (2/CU), 16 independent groups of 32
  k_scan<<<NWG, 512, 0, stream>>>(xin, QpT, RpT, WgT, bg, VT, hs, act, U, bar);

  // conv window-max + final linear
  k_combine<<<512, 256, 0, stream>>>(U, bc3, bc4, bc5, W_lin, b_lin, (float*)d_out);
}

// Round 16
// 5356.860 us; speedup vs baseline: 1.1457x; 1.1457x over previous
//
#include <hip/hip_runtime.h>

#define DI __device__ __forceinline__

typedef __attribute__((ext_vector_type(4))) float  f32x4;
typedef __attribute__((ext_vector_type(8))) short  s16x8;
typedef __attribute__((ext_vector_type(8))) __bf16 bf16x8;
typedef unsigned long long u64;

// ---------------- constants ----------------
constexpr int S_   = 256;
constexpr int B_   = 512;
constexpr int KP_  = 320;   // padded 300
constexpr int ALD_ = 832;   // act row: [xt 0..320 | htm 320..832]
constexpr int NRING = 34;
constexpr int NWG  = 512;   // 16 groups x 32 WGs; 2 WGs per CU
constexpr size_t HSLOT = 512 * 512;

// ---------------- workspace layout (bytes) ----------------
constexpr size_t OFF_XIN = 0;                              // bf16 [S][B][320]
constexpr size_t SZ_XIN  = (size_t)S_ * B_ * KP_ * 2;
constexpr size_t OFF_U   = OFF_XIN + SZ_XIN;               // f32 [B][S][64]
constexpr size_t SZ_U    = (size_t)B_ * S_ * 64 * 4;
constexpr size_t OFF_HS  = OFF_U + SZ_U;                   // bf16 ring [34][512][512]
constexpr size_t SZ_HS   = (size_t)NRING * HSLOT * 2;
constexpr size_t OFF_ACT = OFF_HS + SZ_HS;                 // bf16 [512][832]
constexpr size_t SZ_ACT  = (size_t)B_ * ALD_ * 2;
constexpr size_t OFF_WPT = OFF_ACT + SZ_ACT;               // bf16 [320][320]
constexpr size_t SZ_WPT  = (size_t)320 * 320 * 2;
constexpr size_t OFF_QPT = OFF_WPT + SZ_WPT;               // bf16 [320][512]
constexpr size_t SZ_QPT  = (size_t)320 * 512 * 2;
constexpr size_t OFF_RPT = OFF_QPT + SZ_QPT;               // bf16 [512][320]
constexpr size_t SZ_RPT  = (size_t)512 * 320 * 2;
constexpr size_t OFF_WGT = OFF_RPT + SZ_RPT;               // bf16 [2048][832], n'=4c+g
constexpr size_t SZ_WGT  = (size_t)2048 * 832 * 2;
constexpr size_t OFF_BG  = OFF_WGT + SZ_WGT;               // f32 [2048], n' order
constexpr size_t SZ_BG   = 2048 * 4;
constexpr size_t OFF_VT  = OFF_BG + SZ_BG;                 // bf16 [64][512]
constexpr size_t SZ_VT   = (size_t)64 * 512 * 2;
constexpr size_t OFF_BAR = OFF_VT + SZ_VT;                 // u32: per group 64 u32
constexpr size_t SZ_BAR  = 8192;
constexpr size_t WS_NEED = OFF_BAR + SZ_BAR;

// ---------------- helpers ----------------
DI unsigned short f2bf(float x) {
  unsigned int u = __float_as_uint(x);
  unsigned int r = (u + 0x7FFFu + ((u >> 16) & 1u)) >> 16;
  return (unsigned short)r;
}
DI float bf2f(unsigned short h) { return __uint_as_float(((unsigned int)h) << 16); }

DI float sigm(float x) {
  float e = __builtin_amdgcn_exp2f(x * -1.44269504088896f);
  return __builtin_amdgcn_rcpf(1.0f + e);
}
DI float tanh_(float x) {
  x = fminf(fmaxf(x, -15.0f), 15.0f);
  float e = __builtin_amdgcn_exp2f(x * 2.88539008177793f);
  return (e - 1.0f) * __builtin_amdgcn_rcpf(e + 1.0f);
}
DI bf16x8 asbf(s16x8 v) { return __builtin_bit_cast(bf16x8, v); }

// ---- LLC-coherent (sc0 sc1) accesses, compiler-managed ----
DI u64 ld_sys_u64(const void* p) {
  return __hip_atomic_load((const u64*)p, __ATOMIC_RELAXED, __HIP_MEMORY_SCOPE_SYSTEM);
}
DI void st_sys_u64(void* p, u64 v) {
  __hip_atomic_store((u64*)p, v, __ATOMIC_RELAXED, __HIP_MEMORY_SCOPE_SYSTEM);
}
DI unsigned int ld_sys_u32(const unsigned int* p) {
  return __hip_atomic_load(p, __ATOMIC_RELAXED, __HIP_MEMORY_SCOPE_SYSTEM);
}
DI void st_sys_u32(unsigned int* p, unsigned int v) {
  __hip_atomic_store(p, v, __ATOMIC_RELAXED, __HIP_MEMORY_SCOPE_SYSTEM);
}
template<int N> DI void wait_vm() {
  asm volatile("s_waitcnt vmcnt(%0)" :: "n"(N) : "memory");
}

// ---------------- 2-team K-split GEMM, M=32 N=64 (512 threads) ------------
// R13-proven core. Team tm = tid>>8 handles k-tiles {tm, tm+2, ...} into
// acc[2] (wave tile 16x32). A via sc0sc1 u64, depth-2; B plain cached.
// Accumulates into caller's acc (callable twice for split-K ranges).
template<int NK>
DI void gemm2(const unsigned short* Ab, int lda,
              const unsigned short* Bb, int ldb,
              short* sA, short* sB, f32x4 acc[2])
{
  constexpr int NR = (NK + 1) / 2;
  const int tid  = threadIdx.x;
  const int tm   = tid >> 8;
  const int t8   = tid & 255;
  const int lane = tid & 63;
  const int l15  = lane & 15;
  const int kseg = (lane >> 4) * 8;
  const int w    = (tid >> 6) & 3;
  const int wm = w >> 1, wn = w & 1;
  const int sArow = t8 >> 3, sAcol = (t8 & 7) * 4;
  const int sBrow = t8 >> 2, sBcol = (t8 & 3) * 8;
  const unsigned short* gA = Ab + sArow * lda + sAcol;
  const unsigned short* gB = Bb + sBrow * ldb + sBcol;
  short* tA = sA + tm * 2048;
  short* tB = sB + tm * 4096;
  const int aoff = sArow * 32 + sAcol;
  const int boff = sBrow * 32 + sBcol;
  const int afr  = (wm * 16 + l15) * 32 + kseg;

  u64 a0, a1 = 0, b00, b01, b10 = 0, b11 = 0;
  a0  = ld_sys_u64(gA + tm * 32);
  b00 = ((const u64*)(gB + tm * 32))[0];
  b01 = ((const u64*)(gB + tm * 32))[1];
  if (2 + tm < NK) {
    a1  = ld_sys_u64(gA + (2 + tm) * 32);
    b10 = ((const u64*)(gB + (2 + tm) * 32))[0];
    b11 = ((const u64*)(gB + (2 + tm) * 32))[1];
  }
  *(u64*)&tA[aoff] = a0;
  *(u64*)&tB[boff] = b00; *(u64*)&tB[boff + 4] = b01;
  __syncthreads();
  #pragma unroll
  for (int j = 0; j < NR; ++j) {
    const int curA = (j & 1) * 1024, curB = (j & 1) * 2048;
    if (j + 2 < NR) {
      const int kt = (j + 2) * 2 + tm;
      if (kt < NK) {
        if ((j & 1) == 0) { a0 = ld_sys_u64(gA + kt * 32);
                            b00 = ((const u64*)(gB + kt * 32))[0];
                            b01 = ((const u64*)(gB + kt * 32))[1]; }
        else              { a1 = ld_sys_u64(gA + kt * 32);
                            b10 = ((const u64*)(gB + kt * 32))[0];
                            b11 = ((const u64*)(gB + kt * 32))[1]; }
      }
    }
    if (j * 2 + tm < NK) {
      s16x8 Af = *(const s16x8*)&tA[curA + afr];
      #pragma unroll
      for (int ni = 0; ni < 2; ++ni) {
        s16x8 Bf = *(const s16x8*)&tB[curB + (wn * 32 + ni * 16 + l15) * 32 + kseg];
        acc[ni] = __builtin_amdgcn_mfma_f32_16x16x32_bf16(asbf(Af), asbf(Bf), acc[ni], 0, 0, 0);
      }
    }
    if (j + 1 < NR) {
      const int kt = (j + 1) * 2 + tm;
      const int nxtA = ((j + 1) & 1) * 1024, nxtB = ((j + 1) & 1) * 2048;
      if (kt < NK) {
        if ((j & 1) == 0) { *(u64*)&tA[nxtA + aoff] = a1;
                            *(u64*)&tB[nxtB + boff] = b10; *(u64*)&tB[nxtB + boff + 4] = b11; }
        else              { *(u64*)&tA[nxtA + aoff] = a0;
                            *(u64*)&tB[nxtB + boff] = b00; *(u64*)&tB[nxtB + boff + 4] = b01; }
      }
    }
    __syncthreads();
  }
}

// team1 acc -> rbuf [8][256] (stride-1), team0 adds into its acc
DI void reduce2(f32x4 acc[2], float* rbuf) {
  const int tid = threadIdx.x, t8 = tid & 255;
  if (tid >= 256) {
    #pragma unroll
    for (int ni = 0; ni < 2; ++ni)
      #pragma unroll
      for (int r = 0; r < 4; ++r)
        rbuf[(ni * 4 + r) * 256 + t8] = acc[ni][r];
  }
  __syncthreads();
  if (tid < 256) {
    #pragma unroll
    for (int ni = 0; ni < 2; ++ni)
      #pragma unroll
      for (int r = 0; r < 4; ++r)
        acc[ni][r] += rbuf[(ni * 4 + r) * 256 + t8];
  }
}

// team0 epilogue iterator over the 32x64 tile: f(row, col, val)
template<typename F>
DI void epiloop32(f32x4 acc[2], F&& f) {
  const int lane = threadIdx.x & 63;
  const int w = (threadIdx.x >> 6) & 3, wm = w >> 1, wn = w & 1;
  #pragma unroll
  for (int ni = 0; ni < 2; ++ni)
    #pragma unroll
    for (int r = 0; r < 4; ++r)
      f(wm * 16 + (lane >> 4) * 4 + r, wn * 32 + ni * 16 + (lane & 15), acc[ni][r]);
}

// pack-store a 32x64 u16 LDS tile to system memory (512 threads, 1 u64 each)
DI void pack_store32(const unsigned short* lds16, unsigned short* dstbase, int ldd) {
  const u64* l64 = (const u64*)lds16;
  const int i = threadIdx.x;
  const int row = i >> 4, q = i & 15;
  st_sys_u64(dstbase + row * ldd + q * 4, l64[i]);
}

// ---------------- k_proj building blocks (256 threads) ----------
template<int NK, int KREAL>
DI void gemm_f32A(const float* Af, int lda,
                  const unsigned short* Bb, int ldb,
                  short* sA, short* sB, f32x4 acc[2][2])
{
  const int tid  = threadIdx.x;
  const int lane = tid & 63;
  const int w = tid >> 6, wm = w >> 1, wn = w & 1;
  const float* ga = Af + (tid >> 2) * lda;
  const int cseg  = (tid & 3) * 8;
  const unsigned short* gb = Bb + (tid >> 2) * ldb + (tid & 3) * 8;
  const int arow0 = (wm * 32 + (lane & 15)) * 32 + (lane >> 4) * 8;
  const int brow0 = (wn * 32 + (lane & 15)) * 32 + (lane >> 4) * 8;

  auto loadA = [&](int k) -> s16x8 {
    s16x8 r;
    const int c0 = k * 32 + cseg;
    if (c0 + 8 <= KREAL) {
      float4 f0 = *(const float4*)(ga + c0);
      float4 f1 = *(const float4*)(ga + c0 + 4);
      r[0] = (short)f2bf(f0.x); r[1] = (short)f2bf(f0.y);
      r[2] = (short)f2bf(f0.z); r[3] = (short)f2bf(f0.w);
      r[4] = (short)f2bf(f1.x); r[5] = (short)f2bf(f1.y);
      r[6] = (short)f2bf(f1.z); r[7] = (short)f2bf(f1.w);
    } else {
      #pragma unroll
      for (int j = 0; j < 8; ++j) {
        float x = (c0 + j < KREAL) ? ga[c0 + j] : 0.0f;
        r[j] = (short)f2bf(x);
      }
    }
    return r;
  };

  s16x8 va = loadA(0);
  s16x8 vb = *(const s16x8*)gb;
  *(s16x8*)&sA[tid * 8] = va;
  *(s16x8*)&sB[tid * 8] = vb;
  __syncthreads();
  for (int k = 0; k < NK; ++k) {
    const int cur = (k & 1) * 2048;
    if (k + 1 < NK) {
      va = loadA(k + 1);
      vb = *(const s16x8*)(gb + (k + 1) * 32);
    }
    s16x8 a0 = *(const s16x8*)&sA[cur + arow0];
    s16x8 a1 = *(const s16x8*)&sA[cur + arow0 + 16 * 32];
    s16x8 b0 = *(const s16x8*)&sB[cur + brow0];
    s16x8 b1 = *(const s16x8*)&sB[cur + brow0 + 16 * 32];
    acc[0][0] = __builtin_amdgcn_mfma_f32_16x16x32_bf16(asbf(a0), asbf(b0), acc[0][0], 0, 0, 0);
    acc[0][1] = __builtin_amdgcn_mfma_f32_16x16x32_bf16(asbf(a0), asbf(b1), acc[0][1], 0, 0, 0);
    acc[1][0] = __builtin_amdgcn_mfma_f32_16x16x32_bf16(asbf(a1), asbf(b0), acc[1][0], 0, 0, 0);
    acc[1][1] = __builtin_amdgcn_mfma_f32_16x16x32_bf16(asbf(a1), asbf(b1), acc[1][1], 0, 0, 0);
    if (k + 1 < NK) {
      const int nxt = ((k + 1) & 1) * 2048;
      *(s16x8*)&sA[nxt + tid * 8] = va;
      *(s16x8*)&sB[nxt + tid * 8] = vb;
    }
    __syncthreads();
  }
}

template<typename F>
DI void epiloop(f32x4 acc[2][2], F&& f) {
  const int lane = threadIdx.x & 63;
  const int w = (threadIdx.x & 255) >> 6, wm = w >> 1, wn = w & 1;
  #pragma unroll
  for (int mi = 0; mi < 2; ++mi)
    #pragma unroll
    for (int ni = 0; ni < 2; ++ni)
      #pragma unroll
      for (int r = 0; r < 4; ++r) {
        const int rowl = wm * 32 + mi * 16 + (lane >> 4) * 4 + r;
        const int coll = wn * 32 + ni * 16 + (lane & 15);
        f(rowl, coll, acc[mi][ni][r]);
      }
}

// ---------------- prep kernels ----------------
__global__ void k_prep_wpt(const float* __restrict__ Wi, unsigned short* __restrict__ WpT) {
  int i = blockIdx.x * 256 + threadIdx.x;
  if (i >= 320 * 320) return;
  int n = i / 320, k = i % 320;
  float v = (n < 300 && k < 300) ? Wi[k * 300 + n] : 0.0f;
  WpT[i] = f2bf(v);
}
__global__ void k_prep_qpt(const float* __restrict__ Q, unsigned short* __restrict__ QpT) {
  int i = blockIdx.x * 256 + threadIdx.x;
  if (i >= 320 * 512) return;
  int n = i >> 9, k = i & 511;
  float v = (n < 300) ? Q[k * 300 + n] : 0.0f;
  QpT[i] = f2bf(v);
}
__global__ void k_prep_rpt(const float* __restrict__ R, unsigned short* __restrict__ RpT) {
  int i = blockIdx.x * 256 + threadIdx.x;
  if (i >= 512 * 320) return;
  int n = i / 320, k = i % 320;
  float v = (k < 300) ? R[k * 512 + n] : 0.0f;
  RpT[i] = f2bf(v);
}
// n' = 4c+g ordering: col = g*512 + c
__global__ void k_prep_wgt(const float* __restrict__ Wih, const float* __restrict__ Whh,
                           unsigned short* __restrict__ WgT) {
  int i = blockIdx.x * 256 + threadIdx.x;
  if (i >= 2048 * 832) return;
  int np = i / 832, k = i % 832;
  int c = np >> 2, g = np & 3, col = g * 512 + c;
  float v = 0.0f;
  if (k < 300) v = Wih[k * 2048 + col];
  else if (k >= 320) v = Whh[(k - 320) * 2048 + col];
  WgT[i] = f2bf(v);
}
__global__ void k_prep_bg(const float* __restrict__ bih, const float* __restrict__ bhh,
                          float* __restrict__ bg) {
  int i = blockIdx.x * 256 + threadIdx.x;
  if (i >= 2048) return;
  int c = i >> 2, g = i & 3, col = g * 512 + c;
  bg[i] = bih[col] + bhh[col];
}
__global__ void k_prep_vt(const float* __restrict__ Wc3, const float* __restrict__ Wc4,
                          const float* __restrict__ Wc5, unsigned short* __restrict__ VT) {
  int i = blockIdx.x * 256 + threadIdx.x;
  if (i >= 64 * 512) return;
  int j = i >> 9, k = i & 511;
  float v = 0.0f;
  if (j < 9)       { int f = j / 3,  dt = j % 3;        v = Wc3[(f * 3 + dt) * 512 + k]; }
  else if (j < 21) { int jj = j - 9;  int f = jj / 4, dt = jj % 4; v = Wc4[(f * 4 + dt) * 512 + k]; }
  else if (j < 36) { int jj = j - 21; int f = jj / 5, dt = jj % 5; v = Wc5[(f * 5 + dt) * 512 + k]; }
  VT[i] = f2bf(v);
}
__global__ void k_wsfail(float* out, int n, float v) {
  int i = blockIdx.x * 256 + threadIdx.x;
  if (i < n) out[i] = -v;
}

// ---------------- input projection ----------------
__global__ __launch_bounds__(256) void k_proj(const float* __restrict__ x,
                                              const unsigned short* __restrict__ WpT,
                                              const float* __restrict__ b_in,
                                              unsigned short* __restrict__ xin) {
  __shared__ short sA[4096], sB[4096];
  const int m0 = blockIdx.x * 64, n0 = blockIdx.y * 64;
  f32x4 acc[2][2];
  const f32x4 z = {0.f, 0.f, 0.f, 0.f};
  acc[0][0] = z; acc[0][1] = z; acc[1][0] = z; acc[1][1] = z;
  gemm_f32A<10, 300>(x + (size_t)m0 * 300, 300, WpT + n0 * 320, 320, sA, sB, acc);
  epiloop(acc, [&](int rowl, int coll, float vacc) {
    const int row = m0 + rowl, col = n0 + coll;
    float o = 0.0f;
    if (col < 300) o = tanh_(vacc + b_in[col]);
    const int b = row >> 8, s = row & 255;
    xin[(size_t)(s * 512 + b) * KP_ + col] = f2bf(o);
  });
}

// ---------------- persistent scan kernel ----------------
// 512 WGs x 512 threads = 16 independent groups of 32 WGs; group g owns
// batch rows 32g..32g+31; 2 WGs co-resident per CU. Cross-WG data via
// sc0sc1 only. Per step: TWO group barriers (b1 after P1, b3 after h)
// + a producer-flag wait for P2 that overlaps with the Gx sub-GEMM
// (P3's K-range [0:320], which depends only on xt and runs right after b1).
__global__ __launch_bounds__(512, 4) void k_scan(
    const unsigned short* __restrict__ xin,
    const unsigned short* __restrict__ QpT,
    const unsigned short* __restrict__ RpT,
    const unsigned short* __restrict__ WgT,
    const float* __restrict__ bg,
    const unsigned short* __restrict__ VT,
    unsigned short* __restrict__ hs,
    unsigned short* __restrict__ act,
    float* __restrict__ U,
    unsigned int* __restrict__ bar)
{
  __shared__ short sA[4096];                  // 2 teams x 2 bufs x 1024
  __shared__ short sB[8192];                  // 2 teams x 2 bufs x 2048
  __shared__ float rbuf[2048];                // team reduction (8KB)
  __shared__ float gbuf[2048];                // P3 gates f32 32x64 (8KB)
  __shared__ unsigned short pbuf[2048];       // 32x64 bf16 preload (4KB)
  __shared__ unsigned short obuf[2048];       // 32x64 bf16 out staging (4KB)
  const int wg   = blockIdx.x;
  const int grp  = wg >> 5;       // 16 groups; rows 32*grp .. 32*grp+31
  const int l    = wg & 31;
  const int tid  = threadIdx.x;
  const f32x4 z = {0.f, 0.f, 0.f, 0.f};

  const int gm0 = grp * 32;             // batch-row tile
  const int gn0 = l * 64;               // P3 gate-col tile (n' order)
  float c_state = 0.f;                  // 1 cell/thread (32 rows x 16 hc)
  const int crow = tid >> 4, ccl = tid & 15;       // cell coords
  const float4 cb = *(const float4*)&bg[gn0 + ccl * 4];

  unsigned int* cnt  = bar + grp * 64;        // group barrier counter
  unsigned int* p2f  = bar + grp * 64 + 32;   // 8 P2-completion flags
  int ep = 0;
  auto bar_sync = [&]() {
    wait_vm<0>();
    __syncthreads();
    if (tid == 0) {
      __hip_atomic_fetch_add(cnt, 1u, __ATOMIC_RELAXED, __HIP_MEMORY_SCOPE_AGENT);
      const unsigned tgt = (unsigned)(ep + 1) * 32u;
      while (__hip_atomic_load(cnt, __ATOMIC_RELAXED, __HIP_MEMORY_SCOPE_AGENT) < tgt)
        __builtin_amdgcn_s_sleep(1);
    }
    __syncthreads();
    ++ep;
  };

  for (int t = 0; t < S_; ++t) {
    const unsigned short* hst = hs + (size_t)(t % NRING) * HSLOT;
    unsigned short*       hso = hs + (size_t)((t + 1) % NRING) * HSLOT;

    // hoisted preloads (latency hides under P1)
    u64 xpre = 0, hpre = 0;
    const int prow = tid >> 4, pq = tid & 15;
    if (l < 5)
      xpre = *(const u64*)(xin + ((size_t)t * 512 + gm0 + prow) * KP_ + l * 64 + pq * 4);
    if (l < 8)
      hpre = ld_sys_u64(hst + (gm0 + prow) * 512 + l * 64 + pq * 4);

    // ---- P1: act[:,0:320] = 2*sigm(h_{t-1} @ Q) * xin_t  (5 tiles of 32x64)
    if (l < 5) {
      const int n0 = l * 64;
      ((u64*)pbuf)[tid] = xpre;
      f32x4 acc[2] = {z, z};
      gemm2<16>(hst + gm0 * 512, 512, QpT + n0 * 512, 512, sA, sB, acc);
      reduce2(acc, rbuf);
      if (tid < 256) {
        epiloop32(acc, [&](int row, int col, float v) {
          obuf[row * 64 + col] = f2bf(2.0f * sigm(v) * bf2f(pbuf[row * 64 + col]));
        });
      }
      __syncthreads();
      pack_store32(obuf, act + gm0 * ALD_ + n0, ALD_);
    }
    bar_sync();   // b1: xt visible

    // ---- P2 (WGs 0-7): act[:,320:832] = 2*sigm(xt @ R) * h_{t-1}; post flag
    if (l < 8) {
      const int n0 = l * 64;
      ((u64*)pbuf)[tid] = hpre;
      f32x4 acc[2] = {z, z};
      gemm2<10>(act + gm0 * ALD_, ALD_, RpT + n0 * KP_, KP_, sA, sB, acc);
      reduce2(acc, rbuf);
      if (tid < 256) {
        epiloop32(acc, [&](int row, int col, float v) {
          obuf[row * 64 + col] = f2bf(2.0f * sigm(v) * bf2f(pbuf[row * 64 + col]));
        });
      }
      __syncthreads();
      pack_store32(obuf, act + gm0 * ALD_ + 320 + n0, ALD_);
      wait_vm<0>();          // drain ht' stores to LLC
      __syncthreads();
      if (tid == 0) st_sys_u32(&p2f[l], (unsigned)(t + 1));
    }

    // ---- P3a (all WGs): Gx = xt @ Wg[0:320]  (depends only on b1)
    f32x4 acc[2] = {z, z};
    gemm2<10>(act + gm0 * ALD_, ALD_, WgT + gn0 * 832, 832, sA, sB, acc);

    // ---- wait for all 8 P2 flags (overlapped by Gx for WGs 8-31)
    {
      const unsigned tag = (unsigned)(t + 1);
      if (tid < 64) {
        while (!__all(ld_sys_u32(&p2f[tid & 7]) >= tag))
          __builtin_amdgcn_s_sleep(1);
      }
      __syncthreads();
    }

    // ---- P3b: Gh = ht' @ Wg[320:832], accumulate; then cell update
    {
      gemm2<16>(act + gm0 * ALD_ + 320, ALD_, WgT + gn0 * 832 + 320, 832, sA, sB, acc);
      reduce2(acc, rbuf);
      if (tid < 256) {
        epiloop32(acc, [&](int row, int col, float v) {
          gbuf[row * 64 + col] = v;
        });
      }
      __syncthreads();
      {  // 512 cells: thread (crow, ccl)
        const float iv = gbuf[crow * 64 + ccl * 4 + 0] + cb.x;
        const float fv = gbuf[crow * 64 + ccl * 4 + 1] + cb.y;
        const float gv = gbuf[crow * 64 + ccl * 4 + 2] + cb.z;
        const float ov = gbuf[crow * 64 + ccl * 4 + 3] + cb.w;
        const float cn = sigm(fv) * c_state + sigm(iv) * tanh_(gv);
        const float h  = sigm(ov) * tanh_(cn);
        c_state = cn;
        obuf[crow * 16 + ccl] = f2bf(h);
      }
      __syncthreads();
      if (tid < 128) {   // store h slice (32 rows x 16 cols) to ring
        const u64* h64 = (const u64*)obuf;
        const int row = tid >> 2, q = tid & 3;
        st_sys_u64(hso + (gm0 + row) * 512 + l * 16 + q * 4, h64[row * 4 + q]);
      }
    }
    bar_sync();   // b3: h_t visible

    // ---- convU every 32 steps: WG l covers timestep 32c+l for its rows
    if ((t & 31) == 31) {
      const int c = t >> 5;
      const int tglob = 32 * c + l;
      const int slot = (tglob + 1) % NRING;
      f32x4 acu[2] = {z, z};
      gemm2<16>(hs + (size_t)slot * HSLOT + (size_t)gm0 * 512, 512, VT, 512, sA, sB, acu);
      reduce2(acu, rbuf);
      if (tid < 256) {
        epiloop32(acu, [&](int row, int col, float v) {
          U[((size_t)(gm0 + row) * 256 + tglob) * 64 + col] = v;
        });
      }
      __syncthreads();
    }
  }
}

// window-sum + relu + global max pool + final linear
__global__ __launch_bounds__(256) void k_combine(const float* __restrict__ U,
                                                 const float* __restrict__ bc3,
                                                 const float* __restrict__ bc4,
                                                 const float* __restrict__ bc5,
                                                 const float* __restrict__ Wl,
                                                 const float* __restrict__ bl,
                                                 float* __restrict__ out) {
  const int b = blockIdx.x;
  const int p = threadIdx.x;
  const float* Ub = U + (size_t)b * (256 * 64);
  float v[9];
  #pragma unroll
  for (int j = 0; j < 9; ++j) v[j] = -1e30f;
  if (p < 254) {
    #pragma unroll
    for (int f = 0; f < 3; ++f)
      v[f] = Ub[(p + 0) * 64 + f * 3 + 0] + Ub[(p + 1) * 64 + f * 3 + 1] + Ub[(p + 2) * 64 + f * 3 + 2];
  }
  if (p < 253) {
    #pragma unroll
    for (int f = 0; f < 3; ++f)
      v[3 + f] = Ub[(p + 0) * 64 + 9 + f * 4 + 0] + Ub[(p + 1) * 64 + 9 + f * 4 + 1] +
                 Ub[(p + 2) * 64 + 9 + f * 4 + 2] + Ub[(p + 3) * 64 + 9 + f * 4 + 3];
  }
  if (p < 252) {
    #pragma unroll
    for (int f = 0; f < 3; ++f)
      v[6 + f] = Ub[(p + 0) * 64 + 21 + f * 5 + 0] + Ub[(p + 1) * 64 + 21 + f * 5 + 1] +
                 Ub[(p + 2) * 64 + 21 + f * 5 + 2] + Ub[(p + 3) * 64 + 21 + f * 5 + 3] +
                 Ub[(p + 4) * 64 + 21 + f * 5 + 4];
  }
  __shared__ float red[4][9];
  const int lane = threadIdx.x & 63, w = threadIdx.x >> 6;
  #pragma unroll
  for (int j = 0; j < 9; ++j) {
    float m = v[j];
    #pragma unroll
    for (int off = 32; off >= 1; off >>= 1) m = fmaxf(m, __shfl_xor(m, off));
    if (lane == 0) red[w][j] = m;
  }
  __syncthreads();
  if (threadIdx.x < 2) {
    const int k = threadIdx.x;
    float o = bl[k];
    #pragma unroll
    for (int j = 0; j < 9; ++j) {
      float m = fmaxf(fmaxf(red[0][j], red[1][j]), fmaxf(red[2][j], red[3][j]));
      float bias = (j < 3) ? bc3[j] : (j < 6) ? bc4[j - 3] : bc5[j - 6];
      o += fmaxf(m + bias, 0.0f) * Wl[j * 2 + k];
    }
    out[b * 2 + k] = o;
  }
}

// ---------------- host launch ----------------
extern "C" void kernel_launch(void* const* d_in, const int* in_sizes, int n_in,
                              void* d_out, int out_size, void* d_ws, size_t ws_size,
                              hipStream_t stream) {
  const float* x     = (const float*)d_in[0];
  const float* W_in  = (const float*)d_in[1];
  const float* b_in  = (const float*)d_in[2];
  const float* Wih   = (const float*)d_in[3];
  const float* Whh   = (const float*)d_in[4];
  const float* bih   = (const float*)d_in[5];
  const float* bhh   = (const float*)d_in[6];
  const float* Q     = (const float*)d_in[7];
  const float* R     = (const float*)d_in[8];
  const float* Wc3   = (const float*)d_in[9];
  const float* bc3   = (const float*)d_in[10];
  const float* Wc4   = (const float*)d_in[11];
  const float* bc4   = (const float*)d_in[12];
  const float* Wc5   = (const float*)d_in[13];
  const float* bc5   = (const float*)d_in[14];
  const float* W_lin = (const float*)d_in[15];
  const float* b_lin = (const float*)d_in[16];

  if (ws_size < WS_NEED) {
    k_wsfail<<<4, 256, 0, stream>>>((float*)d_out, out_size, (float)(ws_size >> 20));
    return;
  }

  char* ws = (char*)d_ws;
  unsigned short* xin = (unsigned short*)(ws + OFF_XIN);
  float*          U   = (float*)(ws + OFF_U);
  unsigned short* hs  = (unsigned short*)(ws + OFF_HS);
  unsigned short* act = (unsigned short*)(ws + OFF_ACT);
  unsigned short* WpT = (unsigned short*)(ws + OFF_WPT);
  unsigned short* QpT = (unsigned short*)(ws + OFF_QPT);
  unsigned short* RpT = (unsigned short*)(ws + OFF_RPT);
  unsigned short* WgT = (unsigned short*)(ws + OFF_WGT);
  float*          bg  = (float*)(ws + OFF_BG);
  unsigned short* VT  = (unsigned short*)(ws + OFF_VT);
  unsigned int*   bar = (unsigned int*)(ws + OFF_BAR);

  // per-replay init: h0 = 0 (ring slot 0), barrier counters/flags = 0
  (void)hipMemsetAsync(hs, 0, HSLOT * 2, stream);
  (void)hipMemsetAsync(bar, 0, SZ_BAR, stream);

  // weight prep
  k_prep_wpt<<<(320 * 320 + 255) / 256, 256, 0, stream>>>(W_in, WpT);
  k_prep_qpt<<<(320 * 512 + 255) / 256, 256, 0, stream>>>(Q, QpT);
  k_prep_rpt<<<(512 * 320 + 255) / 256, 256, 0, stream>>>(R, RpT);
  k_prep_wgt<<<(2048 * 832 + 255) / 256, 256, 0, stream>>>(Wih, Whh, WgT);
  k_prep_bg<<<8, 256, 0, stream>>>(bih, bhh, bg);
  k_prep_vt<<<(64 * 512 + 255) / 256, 256, 0, stream>>>(Wc3, Wc4, Wc5, VT);

  // input projection
  k_proj<<<dim3(131072 / 64, KP_ / 64), 256, 0, stream>>>(x, WpT, b_in, xin);

  // persistent scan: 512 WGs (2/CU), 16 independent groups of 32
  k_scan<<<NWG, 512, 0, stream>>>(xin, QpT, RpT, WgT, bg, VT, hs, act, U, bar);

  // conv window-max + final linear
  k_combine<<<512, 256, 0, stream>>>(U, bc3, bc4, bc5, W_lin, b_lin, (float*)d_out);
}